// Round 12
// baseline (285.197 us; speedup 1.0000x reference)
//
#include <hip/hip_runtime.h>
#include <hip/hip_bf16.h>
#include <stdint.h>

// ---------------------------------------------------------------------------
// CharToWord v12: bidirectional char-GRU + attention pooling.
// v11 post-mortem: 6th structural null on gru (per-word time invariant to
// occupancy/VALU/ILP/barriers/tile). attn measured near HBM roofline
// (4.2 TB/s). v12 REMOVES work: attention is fused into the backward GRU
// sweep (backward step s produces hb_t for t=L-1-s = exactly the attention
// positions). hb is never written to global; attn kernel deleted; hb read
// deleted (~180 MB traffic removed); single chunk (ws per-word halved).
//  - gru_fwd: v11 32-word structure, forward only, writes hf valid rows.
//  - gru_bwd_attn: 16 words/block; per step: backward recurrence (v8 math,
//    proven) + hf_t gather + proj MFMA C[cdim][word]=mfma(Wp_frags, out)
//    where out's hb half is read straight from the recurrence's frag-linear
//    h_s + online softmax (pad mass (20-L)e^{c0} kept).
// ---------------------------------------------------------------------------

typedef unsigned short u16;
typedef float f32x4 __attribute__((ext_vector_type(4)));
typedef __bf16 bf16x8 __attribute__((ext_vector_type(8)));

#if __has_builtin(__builtin_amdgcn_exp2f)
#define EXP2F(x) __builtin_amdgcn_exp2f(x)
#else
#define EXP2F(x) exp2f(x)
#endif
#if __has_builtin(__builtin_amdgcn_rcpf)
#define RCPF(x) __builtin_amdgcn_rcpf(x)
#else
#define RCPF(x) (1.0f / (x))
#endif

#define LOG2E 1.4426950408889634f

__device__ __forceinline__ u16 f2b(float f) {
  uint32_t u = __builtin_bit_cast(uint32_t, f);
  u = u + 0x7FFFu + ((u >> 16) & 1u);
  return (u16)(u >> 16);
}
__device__ __forceinline__ float b2f(u16 s) {
  uint32_t u = ((uint32_t)s) << 16;
  return __builtin_bit_cast(float, u);
}
__device__ __forceinline__ float fast_tanh(float x) {
  return 1.0f - 2.0f * RCPF(EXP2F(2.0f * LOG2E * x) + 1.0f);
}
__device__ __forceinline__ uint32_t cvtpk(float a, float b) {
  uint32_t r;
  asm("v_cvt_pk_bf16_f32 %0, %1, %2" : "=v"(r) : "v"(a), "v"(b));
  return r;
}

// ---------------------------------------------------------------------------
// prep: grid 448 x 256 (identical to v8/v11)
// ---------------------------------------------------------------------------
__global__ void prep_kernel(
    const float* __restrict__ emb,
    const float* __restrict__ wih_f, const float* __restrict__ bih_f,
    const float* __restrict__ wih_b, const float* __restrict__ bih_b,
    const float* __restrict__ bhh_f, const float* __restrict__ bhh_b,
    const float* __restrict__ whh_f_in, const float* __restrict__ whh_b_in,
    const float* __restrict__ wp_in,
    float* __restrict__ xpf_f, float* __restrict__ xpf_b,
    u16* __restrict__ whhf, u16* __restrict__ whhb, u16* __restrict__ wpf) {
  int gid = blockIdx.x * 256 + threadIdx.x;
  if (blockIdx.x < 384) {
    int e = gid;                    // 0..98303
    int d = (e >= 49152) ? 1 : 0;
    int r = e - d * 49152;
    int j = r & 3;
    int e2 = r >> 2;                // 12288
    int cls = e2 % 3;
    int e3 = e2 / 3;                // 4096
    int grp = e3 & 3;
    int e4 = e3 >> 2;               // 1024
    int wv = e4 & 7;
    int c = e4 >> 3;                // 128
    int row = cls * 128 + wv * 16 + grp * 4 + j;
    const float* wih = d ? wih_b : wih_f;
    const float* bih = d ? bih_b : bih_f;
    const float* bhh = d ? bhh_b : bhh_f;
    const float4* e4p = (const float4*)(emb + c * 64);
    const float4* w4p = (const float4*)(wih + row * 64);
    float s = 0.f;
#pragma unroll
    for (int q = 0; q < 16; q++) {
      float4 a = e4p[q], b = w4p[q];
      s += a.x * b.x + a.y * b.y + a.z * b.z + a.w * b.w;
    }
    s += bih[row];
    float scale;
    if (cls < 2) {
      s += bhh[row];
      scale = -LOG2E;
    } else {
      scale = 2.0f * LOG2E;
    }
    (d ? xpf_b : xpf_f)[r] = s * scale;
  } else if (blockIdx.x < 432) {
    int idx = gid - 384 * 256;  // 0..12287
    int d = (idx >= 6144) ? 1 : 0;
    int r = idx - d * 6144;
    int lane = r & 63, kt = (r >> 6) & 3, nt = r >> 8;
    float scale = (nt < 16) ? -LOG2E : 2.0f * LOG2E;  // cls = nt>>3
    int n = nt * 16 + (lane & 15);
    int k0 = kt * 32 + (lane >> 4) * 8;
    const float* w = d ? whh_b_in : whh_f_in;
    u16* o = (d ? whhb : whhf) + r * 8;
    for (int j = 0; j < 8; j++) o[j] = f2b(w[n * 128 + k0 + j] * scale);
  } else {
    int idx = gid - 432 * 256;  // 0..4095
    if (idx < 4096) {
      int lane = idx & 63, kt = (idx >> 6) & 7, nt = idx >> 9;
      int n = nt * 16 + (lane & 15);
      int k0 = kt * 32 + (lane >> 4) * 8;
      u16* o = wpf + idx * 8;
      for (int j = 0; j < 8; j++) o[j] = f2b(wp_in[n * 256 + k0 + j]);
    }
  }
}

// ---------------------------------------------------------------------------
// counting sort by length (bins 1..20); c0 = pad-position attention score.
// ---------------------------------------------------------------------------
__global__ void sort_zero(int* __restrict__ bins) {
  if (threadIdx.x < 32) bins[threadIdx.x] = 0;
}
__global__ void sort_hist(const int* __restrict__ lens, int* __restrict__ bins) {
  __shared__ int hcnt[32];
  int tid = threadIdx.x;
  if (tid < 32) hcnt[tid] = 0;
  __syncthreads();
  int gid = blockIdx.x * 256 + tid;
  int l = lens[gid] & 31;
  atomicAdd(&hcnt[l], 1);
  __syncthreads();
  if (tid < 32 && hcnt[tid]) atomicAdd(&bins[tid], hcnt[tid]);
}
__global__ void sort_scan(const int* __restrict__ bins, int* __restrict__ offsw,
                          const float* __restrict__ bp,
                          const float* __restrict__ ctx,
                          float* __restrict__ c0out) {
  if (threadIdx.x == 0 && blockIdx.x == 0) {
    int off = 0;
    for (int l = 0; l < 32; l++) {
      offsw[l] = off;
      off += bins[l];
    }
    float c0 = 0.f;
    for (int c = 0; c < 128; c++) c0 += fast_tanh(bp[c]) * ctx[c];
    *c0out = c0;
  }
}
__global__ void sort_scat(const int* __restrict__ lens, int* __restrict__ offsw,
                          int* __restrict__ perm) {
  __shared__ int lcnt[32];
  __shared__ int lbase[32];
  int tid = threadIdx.x;
  if (tid < 32) lcnt[tid] = 0;
  __syncthreads();
  int gid = blockIdx.x * 256 + tid;
  int l = lens[gid] & 31;
  int lr = atomicAdd(&lcnt[l], 1);
  __syncthreads();
  if (tid < 32) lbase[tid] = lcnt[tid] ? atomicAdd(&offsw[tid], lcnt[tid]) : 0;
  __syncthreads();
  perm[lbase[l] + lr] = gid;
}

// ---------------------------------------------------------------------------
// gru_fwd: grid nbd x 512. 32 sorted words/block (v11 structure, fwd only).
// Writes hf valid rows (chunk-local compact index). LPT order.
// ---------------------------------------------------------------------------
__global__ __launch_bounds__(512, 4) void gru_fwd(
    const int* __restrict__ chars, const int* __restrict__ lens,
    const int* __restrict__ perm,
    const float* __restrict__ xpf_f,
    const u16* __restrict__ whhf, const float* __restrict__ bhh_f,
    u16* __restrict__ hf, int word_off, int nbd) {
  const int wg = nbd - 1 - blockIdx.x;  // longest-first
  const int tid = threadIdx.x;

  __shared__ int perm_s[32];
  __shared__ unsigned char lens_s[32];
  __shared__ int coff_s[640];
  __shared__ u16 h_s[2][4096];

  if (tid < 32) {
    int p = perm[word_off + wg * 32 + tid];
    perm_s[tid] = p;
    lens_s[tid] = (unsigned char)lens[p];
  }
  for (int i = tid; i < 2048; i += 512) ((uint32_t*)h_s)[i] = 0u;
  __syncthreads();
  for (int i = tid; i < 640; i += 512) {
    int w = i & 31, s = i >> 5;
    coff_s[s * 32 + w] = chars[perm_s[w] * 20 + s] * 384;  // fwd: t = s
  }

  u16* hout = hf + (size_t)wg * 32 * 2560;

  const int wv = tid >> 6, ln = tid & 63, word = ln & 15, grp = ln >> 4;
  const float* xpt = xpf_f + (wv * 4 + grp) * 12;

  bf16x8 Wf[3][4];
#pragma unroll
  for (int cls = 0; cls < 3; cls++) {
    int nt = cls * 8 + wv;
#pragma unroll
    for (int kt = 0; kt < 4; kt++)
      Wf[cls][kt] = *(const bf16x8*)(whhf + (((nt * 4 + kt) * 64 + ln) << 3));
  }
  float4 bhn = *(const float4*)(bhh_f + 256 + wv * 16 + grp * 4);
  bhn.x *= 2.0f * LOG2E; bhn.y *= 2.0f * LOG2E;
  bhn.z *= 2.0f * LOG2E; bhn.w *= 2.0f * LOG2E;

  __syncthreads();

  const int Lmax = lens_s[31];

  const int hw_off =
      (((wv >> 1) * 64) + (word | (((wv & 1) * 2 + (grp >> 1)) << 4))) * 16 +
      (grp & 1) * 8;
  const int sm = wv >> 2, skt = wv & 3;
  const int swl = sm * 16 + word;
  const int sLane = lens_s[swl];
  const int hs_off = (((sm * 4 + skt) * 64 + ln) << 4);
  u16* hsto = hout + (size_t)swl * 2560 + skt * 32 + (grp << 3);

  char* hsb = (char*)h_s;

  float h0[4] = {0.f, 0.f, 0.f, 0.f};
  float h1[4] = {0.f, 0.f, 0.f, 0.f};

#define GSTEP(S, PAR)                                                         \
  {                                                                           \
    int off0 = coff_s[(S) * 32 + word];                                       \
    int off1 = coff_s[(S) * 32 + 16 + word];                                  \
    f32x4 x00 = *(const f32x4*)(xpt + off0);                                  \
    f32x4 x01 = *(const f32x4*)(xpt + off0 + 4);                              \
    f32x4 x02 = *(const f32x4*)(xpt + off0 + 8);                              \
    f32x4 x10 = *(const f32x4*)(xpt + off1);                                  \
    f32x4 x11 = *(const f32x4*)(xpt + off1 + 4);                              \
    f32x4 x12 = *(const f32x4*)(xpt + off1 + 8);                              \
    f32x4 a0 = (f32x4){0.f, 0.f, 0.f, 0.f};                                   \
    f32x4 a1 = (f32x4){0.f, 0.f, 0.f, 0.f};                                   \
    f32x4 a2 = (f32x4){bhn.x, bhn.y, bhn.z, bhn.w};                           \
    f32x4 b0 = (f32x4){0.f, 0.f, 0.f, 0.f};                                   \
    f32x4 b1 = (f32x4){0.f, 0.f, 0.f, 0.f};                                   \
    f32x4 b2 = (f32x4){bhn.x, bhn.y, bhn.z, bhn.w};                           \
    _Pragma("unroll")                                                         \
    for (int kt = 0; kt < 4; kt++) {                                          \
      bf16x8 Hf0 =                                                            \
          *(const bf16x8*)(hsb + (PAR) * 8192 + ((kt * 64 + ln) << 4));       \
      a0 = __builtin_amdgcn_mfma_f32_16x16x32_bf16(Wf[0][kt], Hf0, a0, 0, 0, 0); \
      a1 = __builtin_amdgcn_mfma_f32_16x16x32_bf16(Wf[1][kt], Hf0, a1, 0, 0, 0); \
      a2 = __builtin_amdgcn_mfma_f32_16x16x32_bf16(Wf[2][kt], Hf0, a2, 0, 0, 0); \
    }                                                                         \
    _Pragma("unroll")                                                         \
    for (int kt = 0; kt < 4; kt++) {                                          \
      bf16x8 Hf1 = *(const bf16x8*)(hsb + (PAR) * 8192 +                      \
                                    (((4 + kt) * 64 + ln) << 4));             \
      b0 = __builtin_amdgcn_mfma_f32_16x16x32_bf16(Wf[0][kt], Hf1, b0, 0, 0, 0); \
      b1 = __builtin_amdgcn_mfma_f32_16x16x32_bf16(Wf[1][kt], Hf1, b1, 0, 0, 0); \
      b2 = __builtin_amdgcn_mfma_f32_16x16x32_bf16(Wf[2][kt], Hf1, b2, 0, 0, 0); \
    }                                                                         \
    _Pragma("unroll")                                                         \
    for (int r = 0; r < 4; r++) {                                             \
      float rr = RCPF(1.0f + EXP2F(x00[r] + a0[r]));                          \
      float zz = RCPF(1.0f + EXP2F(x01[r] + a1[r]));                          \
      float na = fmaf(rr, a2[r], x02[r]);                                     \
      float nn = fmaf(-2.0f, RCPF(EXP2F(na) + 1.0f), 1.0f);                   \
      h0[r] = fmaf(zz, h0[r] - nn, nn);                                       \
    }                                                                         \
    {                                                                         \
      uint2 pk = make_uint2(cvtpk(h0[0], h0[1]), cvtpk(h0[2], h0[3]));        \
      *(uint2*)(hsb + ((PAR) ^ 1) * 8192 + hw_off) = pk;                      \
    }                                                                         \
    _Pragma("unroll")                                                         \
    for (int r = 0; r < 4; r++) {                                             \
      float rr = RCPF(1.0f + EXP2F(x10[r] + b0[r]));                          \
      float zz = RCPF(1.0f + EXP2F(x11[r] + b1[r]));                          \
      float na = fmaf(rr, b2[r], x12[r]);                                     \
      float nn = fmaf(-2.0f, RCPF(EXP2F(na) + 1.0f), 1.0f);                   \
      h1[r] = fmaf(zz, h1[r] - nn, nn);                                       \
    }                                                                         \
    {                                                                         \
      uint2 pk = make_uint2(cvtpk(h1[0], h1[1]), cvtpk(h1[2], h1[3]));        \
      *(uint2*)(hsb + ((PAR) ^ 1) * 8192 + 4096 + hw_off) = pk;               \
    }                                                                         \
    __syncthreads();                                                          \
    if ((S) < sLane) {                                                        \
      uint4 v = *(const uint4*)(hsb + ((PAR) ^ 1) * 8192 + hs_off);           \
      *(uint4*)(hsto + (S) * 128) = v;                                        \
    }                                                                         \
  }

  for (int s = 0; s < Lmax; s += 2) {
    GSTEP(s, 0);
    if (s + 1 < Lmax) GSTEP(s + 1, 1);
  }
#undef GSTEP
}

// ---------------------------------------------------------------------------
// gru_bwd_attn: grid nbA x 512. 16 sorted words/block. Backward recurrence
// (v8-proven math) fused with attention: step s covers t = Lw-1-s; out_t's
// hb half is read from the recurrence's frag-linear h_s, hf half gathered
// from global. proj C[cdim][word] = mfma(Wp_frags(regs), out_frag). Online
// softmax per word (32 threads replicate state); pad mass added at end.
// ---------------------------------------------------------------------------
__global__ __launch_bounds__(512, 2) void gru_bwd_attn(
    const int* __restrict__ chars, const int* __restrict__ lens,
    const int* __restrict__ perm,
    const float* __restrict__ xpf_b,
    const u16* __restrict__ whhb, const u16* __restrict__ wpf,
    const float* __restrict__ bhh_b,
    const float* __restrict__ bp, const float* __restrict__ ctx,
    const float* __restrict__ c0p,
    const u16* __restrict__ hf, float* __restrict__ out,
    int word_off, int nbA) {
  const int blk = nbA - 1 - blockIdx.x;  // longest-first
  const int lw0 = blk * 16;
  const int tid = threadIdx.x;

  __shared__ int perm_s[16];
  __shared__ unsigned char lens_s[16];
  __shared__ int coff_s[320];
  __shared__ u16 h_s[2][2048];   // 8 KiB recurrence frag-linear dbuf
  __shared__ u16 ot_hf[2048];    // 4 KiB hf_t frag-linear (kt 0..3)
  __shared__ float part_s[8][16];

  if (tid < 16) {
    int p = perm[word_off + lw0 + tid];
    perm_s[tid] = p;
    lens_s[tid] = (unsigned char)lens[p];
  }
  for (int i = tid; i < 1024; i += 512) ((uint32_t*)h_s)[i] = 0u;
  __syncthreads();
  for (int i = tid; i < 320; i += 512) {
    int w = i & 15, s = i >> 4;
    int L = lens_s[w];
    int t = (s < L) ? (L - 1 - s) : s;
    coff_s[s * 16 + w] = chars[perm_s[w] * 20 + t] * 384;
  }

  const int wv = tid >> 6, ln = tid & 63, word = ln & 15, grp = ln >> 4;
  const float* xpt = xpf_b + (wv * 4 + grp) * 12;

  // Whh' (backward, pre-scaled) fragments: 48 VGPRs
  bf16x8 Wf[3][4];
#pragma unroll
  for (int cls = 0; cls < 3; cls++) {
    int nt = cls * 8 + wv;
#pragma unroll
    for (int kt = 0; kt < 4; kt++)
      Wf[cls][kt] = *(const bf16x8*)(whhb + (((nt * 4 + kt) * 64 + ln) << 3));
  }
  // Wp fragments (A-operand; rows = cdim): 64 VGPRs; wave owns nt = wv
  bf16x8 Pf[8];
#pragma unroll
  for (int kt = 0; kt < 8; kt++)
    Pf[kt] = *(const bf16x8*)(wpf + (((wv * 8 + kt) * 64 + ln) << 3));

  float4 bhn = *(const float4*)(bhh_b + 256 + wv * 16 + grp * 4);
  bhn.x *= 2.0f * LOG2E; bhn.y *= 2.0f * LOG2E;
  bhn.z *= 2.0f * LOG2E; bhn.w *= 2.0f * LOG2E;
  float4 bpv = *(const float4*)(bp + wv * 16 + grp * 4);
  float4 ctxv = *(const float4*)(ctx + wv * 16 + grp * 4);
  const float c0 = *c0p;

  __syncthreads();  // coff_s + h_s zero ready

  const int Lmax = lens_s[15];
  const int Lw = lens_s[word];

  const int hw_off =
      (((wv >> 1) * 64) + (word | (((wv & 1) * 2 + (grp >> 1)) << 4))) * 16 +
      (grp & 1) * 8;
  const int fr_lane = word | (grp << 4);
  const int othf_off = ((wv * 64 + fr_lane) << 4);            // wv<4 write
  const int hbr_off = (((wv - 4) * 64 + fr_lane) << 4);       // wv>=4 read
  // hf gather base for this thread (wv<4): word row, dims (wv*4+grp)*8
  const u16* hfb = hf + (size_t)(lw0 + word) * 2560 + (wv * 4 + grp) * 8;

  char* hsb = (char*)h_s;
  char* otb = (char*)ot_hf;

  float hreg[4] = {0.f, 0.f, 0.f, 0.f};
  float facc[8] = {0.f, 0.f, 0.f, 0.f, 0.f, 0.f, 0.f, 0.f};
  float mrun = -3.0e38f, drun = 0.f;

  for (int s = 0; s < Lmax; s++) {
    const int PAR = (s & 1) * 4096;
    const int NPAR = PAR ^ 4096;

    // hf_t gather (wv<4): t clamped for inactive words (valid row, unused)
    uint4 hfc = make_uint4(0u, 0u, 0u, 0u);
    if (wv < 4) {
      int tl = (s < Lw) ? (Lw - 1 - s) : 0;
      hfc = *(const uint4*)(hfb + tl * 128);
    }

    // backward recurrence
    int off = coff_s[s * 16 + word];
    f32x4 x0 = *(const f32x4*)(xpt + off);
    f32x4 x1 = *(const f32x4*)(xpt + off + 4);
    f32x4 x2 = *(const f32x4*)(xpt + off + 8);
    f32x4 a0 = (f32x4){0.f, 0.f, 0.f, 0.f};
    f32x4 a1 = (f32x4){0.f, 0.f, 0.f, 0.f};
    f32x4 a2 = (f32x4){bhn.x, bhn.y, bhn.z, bhn.w};
#pragma unroll
    for (int kt = 0; kt < 4; kt++) {
      bf16x8 Hf = *(const bf16x8*)(hsb + PAR + ((kt * 64 + ln) << 4));
      a0 = __builtin_amdgcn_mfma_f32_16x16x32_bf16(Wf[0][kt], Hf, a0, 0, 0, 0);
      a1 = __builtin_amdgcn_mfma_f32_16x16x32_bf16(Wf[1][kt], Hf, a1, 0, 0, 0);
      a2 = __builtin_amdgcn_mfma_f32_16x16x32_bf16(Wf[2][kt], Hf, a2, 0, 0, 0);
    }
#pragma unroll
    for (int r = 0; r < 4; r++) {
      float rr = RCPF(1.0f + EXP2F(x0[r] + a0[r]));
      float zz = RCPF(1.0f + EXP2F(x1[r] + a1[r]));
      float na = fmaf(rr, a2[r], x2[r]);
      float nn = fmaf(-2.0f, RCPF(EXP2F(na) + 1.0f), 1.0f);
      hreg[r] = fmaf(zz, hreg[r] - nn, nn);
    }
    {
      uint2 pk = make_uint2(cvtpk(hreg[0], hreg[1]), cvtpk(hreg[2], hreg[3]));
      *(uint2*)(hsb + NPAR + hw_off) = pk;
    }
    // stage hf_t into frag layout (kt 0..3)
    if (wv < 4) *(uint4*)(otb + othf_off) = hfc;
    __syncthreads();

    // proj = Wp @ out_t^T + bp  -> C[cdim][word]
    f32x4 pa = (f32x4){bpv.x, bpv.y, bpv.z, bpv.w};
#pragma unroll
    for (int kt = 0; kt < 4; kt++) {
      bf16x8 Bf = *(const bf16x8*)(otb + ((kt * 64 + ln) << 4));
      pa = __builtin_amdgcn_mfma_f32_16x16x32_bf16(Pf[kt], Bf, pa, 0, 0, 0);
    }
#pragma unroll
    for (int kt = 4; kt < 8; kt++) {
      bf16x8 Bf = *(const bf16x8*)(hsb + NPAR + (((kt - 4) * 64 + ln) << 4));
      pa = __builtin_amdgcn_mfma_f32_16x16x32_bf16(Pf[kt], Bf, pa, 0, 0, 0);
    }
    // hb slice for facc (wv>=4), data ready after barrier above
    uint4 hbv = make_uint4(0u, 0u, 0u, 0u);
    if (wv >= 4) hbv = *(const uint4*)(hsb + NPAR + hbr_off);

    // score partial: sum over this thread's 4 cdims, reduce over grp lanes
    float p = fast_tanh(pa[0]) * ctxv.x + fast_tanh(pa[1]) * ctxv.y +
              fast_tanh(pa[2]) * ctxv.z + fast_tanh(pa[3]) * ctxv.w;
    p += __shfl_xor(p, 16, 64);
    p += __shfl_xor(p, 32, 64);
    if (ln < 16) part_s[wv][ln] = p;
    __syncthreads();

    if (s < Lw) {
      float sc = part_s[0][word] + part_s[1][word] + part_s[2][word] +
                 part_s[3][word] + part_s[4][word] + part_s[5][word] +
                 part_s[6][word] + part_s[7][word];
      float mnew = fmaxf(mrun, sc);
      float scale = EXP2F(LOG2E * (mrun - mnew));
      float e = EXP2F(LOG2E * (sc - mnew));
      drun = drun * scale + e;
      mrun = mnew;
      const u16* pv = (wv < 4) ? (const u16*)&hfc : (const u16*)&hbv;
#pragma unroll
      for (int j = 0; j < 8; j++)
        facc[j] = facc[j] * scale + e * b2f(pv[j]);
    }
  }

  // pad mass: softmax over all 20 positions; pads have score c0, zero rows
  drun += (float)(20 - Lw) * EXP2F(LOG2E * (c0 - mrun));
  float inv = RCPF(drun);
  float* dst = out + (size_t)perm_s[word] * 256 + (wv * 4 + grp) * 8;
  float4 o0 = make_float4(facc[0] * inv, facc[1] * inv, facc[2] * inv,
                          facc[3] * inv);
  float4 o1 = make_float4(facc[4] * inv, facc[5] * inv, facc[6] * inv,
                          facc[7] * inv);
  *(float4*)(dst) = o0;
  *(float4*)(dst + 4) = o1;
}

// ---------------------------------------------------------------------------
extern "C" void kernel_launch(void* const* d_in, const int* in_sizes, int n_in,
                              void* d_out, int out_size, void* d_ws, size_t ws_size,
                              hipStream_t stream) {
  const int* chars = (const int*)d_in[0];
  const int* lens = (const int*)d_in[1];
  const float* emb = (const float*)d_in[2];
  const float* wih_f = (const float*)d_in[3];
  const float* whh_f = (const float*)d_in[4];
  const float* bih_f = (const float*)d_in[5];
  const float* bhh_f = (const float*)d_in[6];
  const float* wih_b = (const float*)d_in[7];
  const float* whh_b = (const float*)d_in[8];
  const float* bih_b = (const float*)d_in[9];
  const float* bhh_b = (const float*)d_in[10];
  const float* wp = (const float*)d_in[11];
  const float* bp = (const float*)d_in[12];
  const float* ctx = (const float*)d_in[13];
  float* outp = (float*)d_out;

  uint8_t* ws = (uint8_t*)d_ws;
  float* xpf_f = (float*)(ws + 0);            // 192 KiB
  float* xpf_b = (float*)(ws + 196608);       // 192 KiB
  u16* whhf = (u16*)(ws + 393216);            // 96 KiB
  u16* whhb = (u16*)(ws + 491520);            // 96 KiB
  u16* wpf = (u16*)(ws + 589824);             // 64 KiB
  int* bins = (int*)(ws + 655360);            // 128 B
  int* offsw = (int*)(ws + 655488);           // 128 B
  float* c0p = (float*)(ws + 655616);         // 64 B
  int* permp = (int*)(ws + 655680);           // 128 KiB
  const size_t H_OFF = 1048576;

  prep_kernel<<<448, 256, 0, stream>>>(emb, wih_f, bih_f, wih_b, bih_b, bhh_f,
                                       bhh_b, whh_f, whh_b, wp, xpf_f, xpf_b,
                                       whhf, whhb, wpf);
  sort_zero<<<1, 64, 0, stream>>>(bins);
  sort_hist<<<128, 256, 0, stream>>>(lens, bins);
  sort_scan<<<1, 64, 0, stream>>>(bins, offsw, bp, ctx, c0p);
  sort_scat<<<128, 256, 0, stream>>>(lens, offsw, permp);

  const size_t per_word = 20 * 128 * 2;  // hf only (bf16), hb never stored
  size_t avail = (ws_size > H_OFF) ? (ws_size - H_OFF) : 0;
  int maxw = (int)(avail / per_word) & ~63;
  if (maxw > 32768) maxw = 32768;
  if (maxw < 64) maxw = 64;

  for (int done = 0; done < 32768;) {
    int nw = (32768 - done < maxw) ? (32768 - done) : maxw;
    u16* hfp = (u16*)(ws + H_OFF);
    int nbd = nw / 32;
    int nbA = nw / 16;
    gru_fwd<<<nbd, 512, 0, stream>>>(chars, lens, permp, xpf_f, whhf, bhh_f,
                                     hfp, done, nbd);
    gru_bwd_attn<<<nbA, 512, 0, stream>>>(chars, lens, permp, xpf_b, whhb,
                                          wpf, bhh_b, bp, ctx, c0p, hfp, outp,
                                          done, nbA);
    done += nw;
  }
}